// Round 13
// baseline (267.085 us; speedup 1.0000x reference)
//
#include <hip/hip_runtime.h>

typedef __attribute__((ext_vector_type(8))) short short8;
typedef __attribute__((ext_vector_type(4))) short short4v;
typedef __attribute__((ext_vector_type(4))) float f32x4;
typedef __attribute__((ext_vector_type(16))) float f32x16;
typedef __attribute__((ext_vector_type(2))) unsigned uint2v;

__device__ __forceinline__ short f2bf(float f) {
  union { float f; unsigned u; } c; c.f = f;
  unsigned r = c.u + 0x7FFFu + ((c.u >> 16) & 1u);
  return (short)(r >> 16);
}
__device__ __forceinline__ float bf2f(short h) {
  union { unsigned u; float f; } c; c.u = ((unsigned)(unsigned short)h) << 16;
  return c.f;
}

// ---- cross-half (lane^32) exchange via permlane32_swap: VALU, no LDS pipe ----
__device__ __forceinline__ void swap32(unsigned& a, unsigned& b) {
#if __has_builtin(__builtin_amdgcn_permlane32_swap)
  uint2v r = __builtin_amdgcn_permlane32_swap(a, b, false, false);
  a = r[0]; b = r[1];
#else
  unsigned a2, b2;
  asm volatile("v_mov_b32 %0, %2\n\t"
               "v_mov_b32 %1, %3\n\t"
               "v_permlane32_swap_b32 %0, %1"
               : "=&v"(a2), "=&v"(b2) : "v"(a), "v"(b));
  a = a2; b = b2;
#endif
}
__device__ __forceinline__ float red_max32(float x) {
  unsigned a = __builtin_bit_cast(unsigned, x), b = a;
  swap32(a, b);
  return fmaxf(__builtin_bit_cast(float, a), __builtin_bit_cast(float, b));
}
__device__ __forceinline__ float red_add32(float x) {
  unsigned a = __builtin_bit_cast(unsigned, x), b = a;
  swap32(a, b);
  return __builtin_bit_cast(float, a) + __builtin_bit_cast(float, b);
}

// -------- prep1: fp32->bf16 convert (x) + transpose+convert all 4 weights --------
__global__ __launch_bounds__(256) void prep1(const float* __restrict__ x,
                                             const float* __restrict__ wq,
                                             const float* __restrict__ wk,
                                             const float* __restrict__ wv,
                                             const float* __restrict__ wo,
                                             short* __restrict__ Xb,
                                             short* __restrict__ WallT,
                                             short* __restrict__ WoT) {
  __shared__ float t[32][33];
  int j = blockIdx.x;
  if (j < 4096) {
    int i = (j * 256 + threadIdx.x) * 8;
    float4 a = *(const float4*)(x + i);
    float4 b = *(const float4*)(x + i + 4);
    short8 o;
    o[0] = f2bf(a.x); o[1] = f2bf(a.y); o[2] = f2bf(a.z); o[3] = f2bf(a.w);
    o[4] = f2bf(b.x); o[5] = f2bf(b.y); o[6] = f2bf(b.z); o[7] = f2bf(b.w);
    *(short8*)(Xb + i) = o;
    return;
  }
  j -= 4096;
  const float* W; short* WT; int C, bx, by;
  if (j < 4096)      { W = wq; WT = WallT;                        C = 2048; bx = j & 63; by = j >> 6; }
  else if (j < 5120) { int r = j - 4096; W = wk; WT = WallT + (size_t)2048 * 2048; C = 512; bx = r & 15; by = r >> 4; }
  else if (j < 6144) { int r = j - 5120; W = wv; WT = WallT + (size_t)2560 * 2048; C = 512; bx = r & 15; by = r >> 4; }
  else               { int r = j - 6144; W = wo; WT = WoT;        C = 2048; bx = r & 63; by = r >> 6; }
  int c0 = bx * 32, r0 = by * 32;
  int tx = threadIdx.x & 31, ty = threadIdx.x >> 5;
  #pragma unroll
  for (int i = 0; i < 4; i++)
    t[ty + i * 8][tx] = W[(size_t)(r0 + ty + i * 8) * C + c0 + tx];
  __syncthreads();
  #pragma unroll
  for (int i = 0; i < 4; i++)
    WT[(size_t)(c0 + ty + i * 8) * 2048 + r0 + tx] = f2bf(t[tx][ty + i * 8]);
}

// ---------------- GEMM (R10 proven 2-phase): C(M,N) = A(M,K)*Bt(N,K)^T ----------------
template<bool OUT_BF16>
__global__ __launch_bounds__(256) void gemm_bt(const short* __restrict__ A,
                                               const short* __restrict__ Bt,
                                               void* __restrict__ Cv,
                                               int M, int N, int K, int ldc) {
  constexpr int BK = 32;
  __shared__ __align__(16) short As[2][128 * BK];
  __shared__ __align__(16) short Bs[2][128 * BK];
  int tid = threadIdx.x;
  int wave = tid >> 6, lane = tid & 63;
  int bm = blockIdx.y * 128, bn = blockIdx.x * 128;
  int wr = (wave >> 1) * 64, wc = (wave & 1) * 64;
  f32x4 acc[4][4];
  #pragma unroll
  for (int m = 0; m < 4; m++)
    #pragma unroll
    for (int n = 0; n < 4; n++) acc[m][n] = (f32x4)0.0f;
  const short* Ab = A + (size_t)bm * K;
  const short* Bb = Bt + (size_t)bn * K;

#define GSTAGE(buf, k0) do {                                                             \
    _Pragma("unroll")                                                                    \
    for (int c = 0; c < 2; c++) {                                                        \
      int g = (wave * 2 + c) * 64 + lane;                                                \
      int row = g >> 2;                                                                  \
      int gc = (g & 3) ^ ((row >> 1) & 3);                                               \
      __builtin_amdgcn_global_load_lds(                                                  \
          (const __attribute__((address_space(1))) void*)(Ab + (size_t)row * K + (k0) + gc * 8), \
          (__attribute__((address_space(3))) void*)(&As[buf][(wave * 2 + c) * 512]), 16, 0, 0);  \
      __builtin_amdgcn_global_load_lds(                                                  \
          (const __attribute__((address_space(1))) void*)(Bb + (size_t)row * K + (k0) + gc * 8), \
          (__attribute__((address_space(3))) void*)(&Bs[buf][(wave * 2 + c) * 512]), 16, 0, 0);  \
    }                                                                                    \
  } while (0)

  GSTAGE(0, 0);
  asm volatile("s_waitcnt vmcnt(0)" ::: "memory");
  __builtin_amdgcn_s_barrier();
  int nt = K / BK;
  for (int t = 0; t < nt; ++t) {
    int buf = t & 1;
    if (t + 1 < nt) GSTAGE(buf ^ 1, (t + 1) * BK);
    short8 af[4], bfr[4];
    #pragma unroll
    for (int m = 0; m < 4; m++) {
      int row = wr + m * 16 + (lane & 15);
      int gc = (lane >> 4) ^ ((row >> 1) & 3);
      af[m] = *(const short8*)&As[buf][row * BK + gc * 8];
    }
    #pragma unroll
    for (int n = 0; n < 4; n++) {
      int row = wc + n * 16 + (lane & 15);
      int gc = (lane >> 4) ^ ((row >> 1) & 3);
      bfr[n] = *(const short8*)&Bs[buf][row * BK + gc * 8];
    }
    __builtin_amdgcn_s_setprio(1);
    #pragma unroll
    for (int m = 0; m < 4; m++)
      #pragma unroll
      for (int n = 0; n < 4; n++)
        acc[m][n] = __builtin_amdgcn_mfma_f32_16x16x32_bf16(af[m], bfr[n], acc[m][n], 0, 0, 0);
    __builtin_amdgcn_s_setprio(0);
    asm volatile("s_waitcnt vmcnt(0)" ::: "memory");
    __builtin_amdgcn_s_barrier();
  }
#undef GSTAGE
  #pragma unroll
  for (int m = 0; m < 4; m++)
    #pragma unroll
    for (int n = 0; n < 4; n++)
      #pragma unroll
      for (int j = 0; j < 4; j++) {
        int row = bm + wr + m * 16 + (lane >> 4) * 4 + j;
        int col = bn + wc + n * 16 + (lane & 15);
        if constexpr (OUT_BF16)
          ((short*)Cv)[(size_t)row * ldc + col] = f2bf(acc[m][n][j]);
        else
          ((float*)Cv)[(size_t)row * ldc + col] = acc[m][n][j];
      }
}

// -------- prep2: RMSNorm+RoPE (Q,K) + V transpose (R10 layout), one launch --------
__global__ __launch_bounds__(256) void prep2(const short* __restrict__ QKV,
                                             const float* __restrict__ cosT,
                                             const float* __restrict__ sinT,
                                             const float* __restrict__ qw,
                                             const float* __restrict__ kw,
                                             short* __restrict__ Qa,
                                             short* __restrict__ Ka,
                                             short* __restrict__ Vt) {
  __shared__ short tsh[32][33];
  int j = blockIdx.x;
  if (j < 20480) {
    int lane = threadIdx.x & 63;
    int job = j * 4 + (threadIdx.x >> 6);
    bool isQ = job < 65536;
    const short* src; short* dst; const float* w; float sc;
    int m;
    if (isQ) {
      m = job >> 4;
      int h = job & 15, b = m >> 11, l = m & 2047;
      src = QKV + (size_t)m * 3072 + h * 128;
      dst = Qa + ((size_t)(b * 16 + h) * 2048 + l) * 128;
      w = qw; sc = 0.12751743563f;   // HD^-0.5 * log2(e)
    } else {
      int j2 = job - 65536;
      m = j2 >> 2;
      int g = j2 & 3, b = m >> 11, l = m & 2047;
      src = QKV + (size_t)m * 3072 + 2048 + g * 128;
      dst = Ka + ((size_t)(b * 4 + g) * 2048 + l) * 128;
      w = kw; sc = 1.0f;
    }
    int l = m & 2047;
    float t1 = bf2f(src[lane]);
    float t2 = bf2f(src[lane + 64]);
    float ss = t1 * t1 + t2 * t2;
    #pragma unroll
    for (int i = 1; i < 64; i <<= 1) ss += __shfl_xor(ss, i);
    float r = rsqrtf(ss * (1.0f / 128.0f) + 1e-6f);
    float n1 = t1 * r * w[lane], n2 = t2 * r * w[lane + 64];
    float c1 = cosT[(size_t)l * 128 + lane], s1 = sinT[(size_t)l * 128 + lane];
    float c2 = cosT[(size_t)l * 128 + 64 + lane], s2 = sinT[(size_t)l * 128 + 64 + lane];
    dst[lane]      = f2bf((n1 * c1 - n2 * s1) * sc);
    dst[lane + 64] = f2bf((n2 * c2 + n1 * s2) * sc);
    return;
  }
  int j2 = j - 20480;
  int bg = j2 >> 8; int b = bg >> 2, g = bg & 3;
  int l0 = (j2 & 63) * 32, d0 = ((j2 >> 6) & 3) * 32;
  int tx = threadIdx.x & 31, ty = threadIdx.x >> 5;
  const short* src = QKV + (size_t)b * 2048 * 3072 + 2560 + g * 128;
  #pragma unroll
  for (int i = 0; i < 4; i++)
    tsh[ty + i * 8][tx] = src[(size_t)(l0 + ty + i * 8) * 3072 + d0 + tx];
  __syncthreads();
  short* dst = Vt + (size_t)bg * 128 * 2048;
  #pragma unroll
  for (int i = 0; i < 4; i++)
    dst[(size_t)(d0 + ty + i * 8) * 2048 + l0 + tx] = tsh[tx][ty + i * 8];
}

// ---------------- flash attention v13: R10 structure, V read direct from L2 ----------------
// Guide Common-mistake #7: V for a (b,g) is 512KB, XCD-pinned -> L2-resident;
// per-iter V slice 16KB is shared by all 4 heads. Drop Vs LDS staging: PV reads
// its A-operand fragments straight from global (16 independent 16B loads,
// hoisted by the compiler under the QK^T chain). K staging (swizzled LDS)
// retained. LDS 64KB -> 32KB; single-barrier pipeline unchanged.
__global__ __launch_bounds__(256, 2) void attn13(const short* __restrict__ Qa,
                                                 const short* __restrict__ Ka,
                                                 const short* __restrict__ Vt,
                                                 short* __restrict__ AO) {
  __shared__ __align__(16) short Ks[2][8192];
  int tid = threadIdx.x, wave = tid >> 6, lane = tid & 63;
  int l31 = lane & 31, hi = lane >> 5;
  int id = blockIdx.x;
  int bg = id & 7;
  int k = id >> 3;
  int qc = (k & 1) ? (64 - k) : k;         // complementary pairing
  int b = bg >> 2, g = bg & 3;
  int h = g * 4 + wave;
  int qbase = qc * 32;
  const short* Qp = Qa + ((size_t)(b * 16 + h) * 2048 + qbase) * 128;
  const short* Kp = Ka + (size_t)(b * 4 + g) * 2048 * 128;
  const short* Vp = Vt + (size_t)(b * 4 + g) * 128 * 2048;

  short8 qf[8];
  #pragma unroll
  for (int kk = 0; kk < 8; kk++)
    qf[kk] = *(const short8*)&Qp[(size_t)l31 * 128 + kk * 16 + hi * 8];

  f32x16 accT[4];
  #pragma unroll
  for (int m = 0; m < 4; m++) accT[m] = (f32x16)0.0f;
  float m_run = -INFINITY, l_run = 0.0f;

  int tmax = qc >> 1;
  int swzk = l31 & 15;

#define STAGE(buf, tt) do {                                                              \
    int kv0s = (tt) * 64;                                                                \
    _Pragma("unroll")                                                                    \
    for (int c4 = 0; c4 < 4; c4++) {                                                     \
      int cs = wave * 4 + c4;                                                            \
      int kvr = cs * 4 + (lane >> 4);                                                    \
      int cc = (lane & 15) ^ (kvr & 15);                                                 \
      __builtin_amdgcn_global_load_lds(                                                  \
        (const __attribute__((address_space(1))) void*)(Kp + (size_t)(kv0s + kvr) * 128 + cc * 8), \
        (__attribute__((address_space(3))) void*)(&Ks[buf][cs * 512]), 16, 0, 0);        \
    }                                                                                    \
  } while (0)

  STAGE(0, 0);
  asm volatile("s_waitcnt vmcnt(0)" ::: "memory");
  __builtin_amdgcn_s_barrier();
  for (int t = 0; t <= tmax; t++) {
    int cur = t & 1;
    if (t < tmax) STAGE(cur ^ 1, t + 1);
    {
      bool diag = (t == tmax);
      bool nf2 = !(diag && !(qc & 1));
      const short* Kc = &Ks[cur][0];
      const short* Vrow = Vp + t * 64;     // V^T fragment base for this kv tile
      f32x16 s0 = (f32x16)0.0f, s1 = (f32x16)0.0f;
      __builtin_amdgcn_s_setprio(1);
      #pragma unroll
      for (int kk = 0; kk < 8; kk++) {
        int gsl = ((2 * kk + hi) ^ swzk) * 8;
        short8 kf0 = *(const short8*)&Kc[l31 * 128 + gsl];
        s0 = __builtin_amdgcn_mfma_f32_32x32x16_bf16(kf0, qf[kk], s0, 0, 0, 0);
        if (nf2) {
          short8 kf1 = *(const short8*)&Kc[l31 * 128 + 4096 + gsl];
          s1 = __builtin_amdgcn_mfma_f32_32x32x16_bf16(kf1, qf[kk], s1, 0, 0, 0);
        }
      }
      __builtin_amdgcn_s_setprio(0);
      if (diag) {
        int qrel = (qc & 1) * 32 + l31;
        #pragma unroll
        for (int r = 0; r < 16; r++) {
          int kvl = (r & 3) + 8 * (r >> 2) + 4 * hi;
          if (kvl > qrel) s0[r] = -INFINITY;
          if (kvl + 32 > qrel) s1[r] = -INFINITY;
        }
      }
      float t8[8];
      #pragma unroll
      for (int i = 0; i < 8; i++) t8[i] = fmaxf(s0[2 * i], s0[2 * i + 1]);
      if (nf2) {
        #pragma unroll
        for (int i = 0; i < 8; i++) t8[i] = fmaxf(t8[i], fmaxf(s1[2 * i], s1[2 * i + 1]));
      }
      float m01 = fmaxf(fmaxf(t8[0], t8[1]), fmaxf(t8[2], t8[3]));
      float m23 = fmaxf(fmaxf(t8[4], t8[5]), fmaxf(t8[6], t8[7]));
      float pmax = red_max32(fmaxf(m01, m23));
      if (!__all(pmax - m_run <= 11.0f)) {
        float mn = fmaxf(m_run, pmax);
        float al = __builtin_amdgcn_exp2f(m_run - mn);
        l_run *= al;
        #pragma unroll
        for (int m = 0; m < 4; m++) accT[m] *= al;
        m_run = mn;
      }
      #pragma unroll
      for (int r = 0; r < 16; r++) s0[r] = __builtin_amdgcn_exp2f(s0[r] - m_run);
      if (nf2) {
        #pragma unroll
        for (int r = 0; r < 16; r++) s1[r] = __builtin_amdgcn_exp2f(s1[r] - m_run);
      }
      float a8[8];
      #pragma unroll
      for (int i = 0; i < 8; i++) a8[i] = s0[2 * i] + s0[2 * i + 1];
      if (nf2) {
        #pragma unroll
        for (int i = 0; i < 8; i++) a8[i] += s1[2 * i] + s1[2 * i + 1];
      }
      float r01 = (a8[0] + a8[1]) + (a8[2] + a8[3]);
      float r23 = (a8[4] + a8[5]) + (a8[6] + a8[7]);
      l_run += red_add32(r01 + r23);

      auto packfrag = [&](const f32x16& sv, int rb) -> short8 {
        union { short8 hh; unsigned u[4]; } P;
        #pragma unroll
        for (int w = 0; w < 2; w++) {
          float a0 = sv[rb + 2 * w],     a1 = sv[rb + 2 * w + 1];
          float b0 = sv[rb + 4 + 2 * w], b1 = sv[rb + 4 + 2 * w + 1];
          unsigned X, Y;
          asm("v_cvt_pk_bf16_f32 %0, %1, %2" : "=v"(X) : "v"(a0), "v"(a1));
          asm("v_cvt_pk_bf16_f32 %0, %1, %2" : "=v"(Y) : "v"(b0), "v"(b1));
          swap32(X, Y);
          P.u[w]     = X;
          P.u[w + 2] = Y;
        }
        return P.hh;
      };
#define PVSTEP(g4, pg) do {                                                             \
        _Pragma("unroll")                                                               \
        for (int m = 0; m < 4; m++) {                                                   \
          short8 vf = *(const short8*)&Vrow[(size_t)(m * 32 + l31) * 2048 + (2 * (g4) + hi) * 8]; \
          accT[m] = __builtin_amdgcn_mfma_f32_32x32x16_bf16(vf, pg, accT[m], 0, 0, 0);  \
        }                                                                               \
      } while (0)
      short8 pg;
      __builtin_amdgcn_s_setprio(1);
      pg = packfrag(s0, 0); PVSTEP(0, pg);
      pg = packfrag(s0, 8); PVSTEP(1, pg);
      if (nf2) {
        pg = packfrag(s1, 0); PVSTEP(2, pg);
        pg = packfrag(s1, 8); PVSTEP(3, pg);
      }
      __builtin_amdgcn_s_setprio(0);
#undef PVSTEP
    }
    asm volatile("s_waitcnt vmcnt(0)" ::: "memory");
    __builtin_amdgcn_s_barrier();
  }
#undef STAGE

  // epilogue: O^T -> O via per-wave LDS transpose, coalesced bf16 store
  __syncthreads();
  float linv = 1.0f / l_run;
  float* T = (float*)(&Ks[0][0]) + wave * 1056;   // 4 x 4224B = 16.9KB <= 32KB
  #pragma unroll
  for (int m = 0; m < 4; m++) {
    #pragma unroll
    for (int r = 0; r < 16; r++)
      T[((r & 3) + 8 * (r >> 2) + 4 * hi) * 33 + l31] = accT[m][r] * linv;
    asm volatile("" ::: "memory");
    #pragma unroll
    for (int it2 = 0; it2 < 4; it2++) {
      int q2 = it2 * 8 + (lane >> 3);
      int d8 = (lane & 7) * 4;
      short4v o;
      #pragma unroll
      for (int kq = 0; kq < 4; kq++) o[kq] = f2bf(T[(d8 + kq) * 33 + q2]);
      *(short4v*)&AO[((size_t)(b * 2048 + qbase + q2)) * 2048 + h * 128 + m * 32 + d8] = o;
    }
    asm volatile("" ::: "memory");
  }
}

// ---------------- launch ----------------
extern "C" void kernel_launch(void* const* d_in, const int* in_sizes, int n_in,
                              void* d_out, int out_size, void* d_ws, size_t ws_size,
                              hipStream_t stream) {
  (void)in_sizes; (void)n_in; (void)out_size; (void)ws_size;
  const float* x    = (const float*)d_in[0];
  const float* cosT = (const float*)d_in[1];
  const float* sinT = (const float*)d_in[2];
  // d_in[3] = mask (causal, structure known; unused)
  const float* wq = (const float*)d_in[4];
  const float* wk = (const float*)d_in[5];
  const float* wv = (const float*)d_in[6];
  const float* wo = (const float*)d_in[7];
  const float* qw = (const float*)d_in[8];
  const float* kw = (const float*)d_in[9];
  float* Out = (float*)d_out;

  char* w = (char*)d_ws;
  short* Xb    = (short*)(w + 0);           // 4096x2048 bf16          16777216 B
  short* WallT = (short*)(w + 16777216);    // [WqT;WkT;WvT] 3072x2048 12582912 B
  short* WoT   = (short*)(w + 29360128);    // 2048x2048                8388608 B
  short* QKV   = (short*)(w + 37748736);    // 4096x3072               25165824 B
  short* Qa    = (short*)(w + 62914560);    // (b,h,2048,128)          16777216 B
  short* Ka    = (short*)(w + 79691776);    // (b,g,2048,128)           4194304 B
  short* Vtr   = (short*)(w + 83886080);    // (b,g,128,2048)           4194304 B
  short* AO    = (short*)(w + 88080384);    // 4096x2048               16777216 B
  // total 104857600 B

  prep1<<<14336, 256, 0, stream>>>(x, wq, wk, wv, wo, Xb, WallT, WoT);
  gemm_bt<true><<<dim3(24, 32), 256, 0, stream>>>(Xb, WallT, QKV, 4096, 3072, 2048, 3072);
  prep2<<<22528, 256, 0, stream>>>(QKV, cosT, sinT, qw, kw, Qa, Ka, Vtr);
  attn13<<<512, 256, 0, stream>>>(Qa, Ka, Vtr, AO);
  gemm_bt<false><<<dim3(16, 32), 256, 0, stream>>>(AO, WoT, Out, 4096, 2048, 2048, 2048);
}

// Round 14
// 205.997 us; speedup vs baseline: 1.2965x; 1.2965x over previous
//
#include <hip/hip_runtime.h>

typedef __attribute__((ext_vector_type(8))) short short8;
typedef __attribute__((ext_vector_type(4))) short short4v;
typedef __attribute__((ext_vector_type(4))) float f32x4;
typedef __attribute__((ext_vector_type(16))) float f32x16;
typedef __attribute__((ext_vector_type(2))) unsigned uint2v;

__device__ __forceinline__ short f2bf(float f) {
  union { float f; unsigned u; } c; c.f = f;
  unsigned r = c.u + 0x7FFFu + ((c.u >> 16) & 1u);
  return (short)(r >> 16);
}
__device__ __forceinline__ float bf2f(short h) {
  union { unsigned u; float f; } c; c.u = ((unsigned)(unsigned short)h) << 16;
  return c.f;
}

// ---- cross-half (lane^32) exchange via permlane32_swap: VALU, no LDS pipe ----
__device__ __forceinline__ void swap32(unsigned& a, unsigned& b) {
#if __has_builtin(__builtin_amdgcn_permlane32_swap)
  uint2v r = __builtin_amdgcn_permlane32_swap(a, b, false, false);
  a = r[0]; b = r[1];
#else
  unsigned a2, b2;
  asm volatile("v_mov_b32 %0, %2\n\t"
               "v_mov_b32 %1, %3\n\t"
               "v_permlane32_swap_b32 %0, %1"
               : "=&v"(a2), "=&v"(b2) : "v"(a), "v"(b));
  a = a2; b = b2;
#endif
}
__device__ __forceinline__ float red_max32(float x) {
  unsigned a = __builtin_bit_cast(unsigned, x), b = a;
  swap32(a, b);
  return fmaxf(__builtin_bit_cast(float, a), __builtin_bit_cast(float, b));
}
__device__ __forceinline__ float red_add32(float x) {
  unsigned a = __builtin_bit_cast(unsigned, x), b = a;
  swap32(a, b);
  return __builtin_bit_cast(float, a) + __builtin_bit_cast(float, b);
}

// -------- prep1: fp32->bf16 convert (x) + transpose+convert all 4 weights --------
__global__ __launch_bounds__(256) void prep1(const float* __restrict__ x,
                                             const float* __restrict__ wq,
                                             const float* __restrict__ wk,
                                             const float* __restrict__ wv,
                                             const float* __restrict__ wo,
                                             short* __restrict__ Xb,
                                             short* __restrict__ WallT,
                                             short* __restrict__ WoT) {
  __shared__ float t[32][33];
  int j = blockIdx.x;
  if (j < 4096) {
    int i = (j * 256 + threadIdx.x) * 8;
    float4 a = *(const float4*)(x + i);
    float4 b = *(const float4*)(x + i + 4);
    short8 o;
    o[0] = f2bf(a.x); o[1] = f2bf(a.y); o[2] = f2bf(a.z); o[3] = f2bf(a.w);
    o[4] = f2bf(b.x); o[5] = f2bf(b.y); o[6] = f2bf(b.z); o[7] = f2bf(b.w);
    *(short8*)(Xb + i) = o;
    return;
  }
  j -= 4096;
  const float* W; short* WT; int C, bx, by;
  if (j < 4096)      { W = wq; WT = WallT;                        C = 2048; bx = j & 63; by = j >> 6; }
  else if (j < 5120) { int r = j - 4096; W = wk; WT = WallT + (size_t)2048 * 2048; C = 512; bx = r & 15; by = r >> 4; }
  else if (j < 6144) { int r = j - 5120; W = wv; WT = WallT + (size_t)2560 * 2048; C = 512; bx = r & 15; by = r >> 4; }
  else               { int r = j - 6144; W = wo; WT = WoT;        C = 2048; bx = r & 63; by = r >> 6; }
  int c0 = bx * 32, r0 = by * 32;
  int tx = threadIdx.x & 31, ty = threadIdx.x >> 5;
  #pragma unroll
  for (int i = 0; i < 4; i++)
    t[ty + i * 8][tx] = W[(size_t)(r0 + ty + i * 8) * C + c0 + tx];
  __syncthreads();
  #pragma unroll
  for (int i = 0; i < 4; i++)
    WT[(size_t)(c0 + ty + i * 8) * 2048 + r0 + tx] = f2bf(t[tx][ty + i * 8]);
}

// ---------------- GEMM (R10 proven 2-phase): C(M,N) = A(M,K)*Bt(N,K)^T ----------------
template<bool OUT_BF16>
__global__ __launch_bounds__(256) void gemm_bt(const short* __restrict__ A,
                                               const short* __restrict__ Bt,
                                               void* __restrict__ Cv,
                                               int M, int N, int K, int ldc) {
  constexpr int BK = 32;
  __shared__ __align__(16) short As[2][128 * BK];
  __shared__ __align__(16) short Bs[2][128 * BK];
  int tid = threadIdx.x;
  int wave = tid >> 6, lane = tid & 63;
  int bm = blockIdx.y * 128, bn = blockIdx.x * 128;
  int wr = (wave >> 1) * 64, wc = (wave & 1) * 64;
  f32x4 acc[4][4];
  #pragma unroll
  for (int m = 0; m < 4; m++)
    #pragma unroll
    for (int n = 0; n < 4; n++) acc[m][n] = (f32x4)0.0f;
  const short* Ab = A + (size_t)bm * K;
  const short* Bb = Bt + (size_t)bn * K;

#define GSTAGE(buf, k0) do {                                                             \
    _Pragma("unroll")                                                                    \
    for (int c = 0; c < 2; c++) {                                                        \
      int g = (wave * 2 + c) * 64 + lane;                                                \
      int row = g >> 2;                                                                  \
      int gc = (g & 3) ^ ((row >> 1) & 3);                                               \
      __builtin_amdgcn_global_load_lds(                                                  \
          (const __attribute__((address_space(1))) void*)(Ab + (size_t)row * K + (k0) + gc * 8), \
          (__attribute__((address_space(3))) void*)(&As[buf][(wave * 2 + c) * 512]), 16, 0, 0);  \
      __builtin_amdgcn_global_load_lds(                                                  \
          (const __attribute__((address_space(1))) void*)(Bb + (size_t)row * K + (k0) + gc * 8), \
          (__attribute__((address_space(3))) void*)(&Bs[buf][(wave * 2 + c) * 512]), 16, 0, 0);  \
    }                                                                                    \
  } while (0)

  GSTAGE(0, 0);
  asm volatile("s_waitcnt vmcnt(0)" ::: "memory");
  __builtin_amdgcn_s_barrier();
  int nt = K / BK;
  for (int t = 0; t < nt; ++t) {
    int buf = t & 1;
    if (t + 1 < nt) GSTAGE(buf ^ 1, (t + 1) * BK);
    short8 af[4], bfr[4];
    #pragma unroll
    for (int m = 0; m < 4; m++) {
      int row = wr + m * 16 + (lane & 15);
      int gc = (lane >> 4) ^ ((row >> 1) & 3);
      af[m] = *(const short8*)&As[buf][row * BK + gc * 8];
    }
    #pragma unroll
    for (int n = 0; n < 4; n++) {
      int row = wc + n * 16 + (lane & 15);
      int gc = (lane >> 4) ^ ((row >> 1) & 3);
      bfr[n] = *(const short8*)&Bs[buf][row * BK + gc * 8];
    }
    __builtin_amdgcn_s_setprio(1);
    #pragma unroll
    for (int m = 0; m < 4; m++)
      #pragma unroll
      for (int n = 0; n < 4; n++)
        acc[m][n] = __builtin_amdgcn_mfma_f32_16x16x32_bf16(af[m], bfr[n], acc[m][n], 0, 0, 0);
    __builtin_amdgcn_s_setprio(0);
    asm volatile("s_waitcnt vmcnt(0)" ::: "memory");
    __builtin_amdgcn_s_barrier();
  }
#undef GSTAGE
  #pragma unroll
  for (int m = 0; m < 4; m++)
    #pragma unroll
    for (int n = 0; n < 4; n++)
      #pragma unroll
      for (int j = 0; j < 4; j++) {
        int row = bm + wr + m * 16 + (lane >> 4) * 4 + j;
        int col = bn + wc + n * 16 + (lane & 15);
        if constexpr (OUT_BF16)
          ((short*)Cv)[(size_t)row * ldc + col] = f2bf(acc[m][n][j]);
        else
          ((float*)Cv)[(size_t)row * ldc + col] = acc[m][n][j];
      }
}

// -------- prep2: RMSNorm+RoPE (Q,K) + V transpose (R10 layout), one launch --------
__global__ __launch_bounds__(256) void prep2(const short* __restrict__ QKV,
                                             const float* __restrict__ cosT,
                                             const float* __restrict__ sinT,
                                             const float* __restrict__ qw,
                                             const float* __restrict__ kw,
                                             short* __restrict__ Qa,
                                             short* __restrict__ Ka,
                                             short* __restrict__ Vt) {
  __shared__ short tsh[32][33];
  int j = blockIdx.x;
  if (j < 20480) {
    int lane = threadIdx.x & 63;
    int job = j * 4 + (threadIdx.x >> 6);
    bool isQ = job < 65536;
    const short* src; short* dst; const float* w; float sc;
    int m;
    if (isQ) {
      m = job >> 4;
      int h = job & 15, b = m >> 11, l = m & 2047;
      src = QKV + (size_t)m * 3072 + h * 128;
      dst = Qa + ((size_t)(b * 16 + h) * 2048 + l) * 128;
      w = qw; sc = 0.12751743563f;   // HD^-0.5 * log2(e)
    } else {
      int j2 = job - 65536;
      m = j2 >> 2;
      int g = j2 & 3, b = m >> 11, l = m & 2047;
      src = QKV + (size_t)m * 3072 + 2048 + g * 128;
      dst = Ka + ((size_t)(b * 4 + g) * 2048 + l) * 128;
      w = kw; sc = 1.0f;
    }
    int l = m & 2047;
    float t1 = bf2f(src[lane]);
    float t2 = bf2f(src[lane + 64]);
    float ss = t1 * t1 + t2 * t2;
    #pragma unroll
    for (int i = 1; i < 64; i <<= 1) ss += __shfl_xor(ss, i);
    float r = rsqrtf(ss * (1.0f / 128.0f) + 1e-6f);
    float n1 = t1 * r * w[lane], n2 = t2 * r * w[lane + 64];
    float c1 = cosT[(size_t)l * 128 + lane], s1 = sinT[(size_t)l * 128 + lane];
    float c2 = cosT[(size_t)l * 128 + 64 + lane], s2 = sinT[(size_t)l * 128 + 64 + lane];
    dst[lane]      = f2bf((n1 * c1 - n2 * s1) * sc);
    dst[lane + 64] = f2bf((n2 * c2 + n1 * s2) * sc);
    return;
  }
  int j2 = j - 20480;
  int bg = j2 >> 8; int b = bg >> 2, g = bg & 3;
  int l0 = (j2 & 63) * 32, d0 = ((j2 >> 6) & 3) * 32;
  int tx = threadIdx.x & 31, ty = threadIdx.x >> 5;
  const short* src = QKV + (size_t)b * 2048 * 3072 + 2560 + g * 128;
  #pragma unroll
  for (int i = 0; i < 4; i++)
    tsh[ty + i * 8][tx] = src[(size_t)(l0 + ty + i * 8) * 3072 + d0 + tx];
  __syncthreads();
  short* dst = Vt + (size_t)bg * 128 * 2048;
  #pragma unroll
  for (int i = 0; i < 4; i++)
    dst[(size_t)(d0 + ty + i * 8) * 2048 + l0 + tx] = tsh[tx][ty + i * 8];
}

// ---------------- flash attention v14: R10 structure + de-interleaved LDS reads ----------------
// Identical sync structure to R10's attn10 (proven 74us). Single change: QK and
// PV fragment loads are hoisted into register arrays BEFORE their MFMA chains,
// so the 16 ds_read_b128 pipeline back-to-back (~12cy issue each) instead of
// paying ~120cy latency serially per load-use pair on the 1-wave/SIMD
// critical chain.
__global__ __launch_bounds__(256, 2) void attn14(const short* __restrict__ Qa,
                                                 const short* __restrict__ Ka,
                                                 const short* __restrict__ Vt,
                                                 short* __restrict__ AO) {
  __shared__ __align__(16) short Ks[2][8192];
  __shared__ __align__(16) short Vs[2][8192];
  int tid = threadIdx.x, wave = tid >> 6, lane = tid & 63;
  int l31 = lane & 31, hi = lane >> 5;
  int id = blockIdx.x;
  int bg = id & 7;
  int k = id >> 3;
  int qc = (k & 1) ? (64 - k) : k;         // complementary pairing
  int b = bg >> 2, g = bg & 3;
  int h = g * 4 + wave;
  int qbase = qc * 32;
  const short* Qp = Qa + ((size_t)(b * 16 + h) * 2048 + qbase) * 128;
  const short* Kp = Ka + (size_t)(b * 4 + g) * 2048 * 128;
  const short* Vp = Vt + (size_t)(b * 4 + g) * 128 * 2048;

  short8 qf[8];
  #pragma unroll
  for (int kk = 0; kk < 8; kk++)
    qf[kk] = *(const short8*)&Qp[(size_t)l31 * 128 + kk * 16 + hi * 8];

  f32x16 accT[4];
  #pragma unroll
  for (int m = 0; m < 4; m++) accT[m] = (f32x16)0.0f;
  float m_run = -INFINITY, l_run = 0.0f;

  int tmax = qc >> 1;
  int swzk = l31 & 15;
  int swzv = (lane >> 1) & 3;              // unused placeholder removed below
  (void)swzv;
  int swzv2 = l31 & 7;                     // PV read swizzle (d & 7), d=m*32+l31

#define STAGE(buf, tt) do {                                                              \
    int kv0s = (tt) * 64;                                                                \
    _Pragma("unroll")                                                                    \
    for (int c4 = 0; c4 < 4; c4++) {                                                     \
      int cs = wave * 4 + c4;                                                            \
      int kvr = cs * 4 + (lane >> 4);                                                    \
      int cc = (lane & 15) ^ (kvr & 15);                                                 \
      __builtin_amdgcn_global_load_lds(                                                  \
        (const __attribute__((address_space(1))) void*)(Kp + (size_t)(kv0s + kvr) * 128 + cc * 8), \
        (__attribute__((address_space(3))) void*)(&Ks[buf][cs * 512]), 16, 0, 0);        \
    }                                                                                    \
    _Pragma("unroll")                                                                    \
    for (int c4 = 0; c4 < 4; c4++) {                                                     \
      int cs = wave * 4 + c4;                                                            \
      int dd = cs * 8 + (lane >> 3);                                                     \
      int jj = (lane & 7) ^ (dd & 7);                                                    \
      __builtin_amdgcn_global_load_lds(                                                  \
        (const __attribute__((address_space(1))) void*)(Vp + (size_t)dd * 2048 + kv0s + jj * 8),    \
        (__attribute__((address_space(3))) void*)(&Vs[buf][cs * 512]), 16, 0, 0);        \
    }                                                                                    \
  } while (0)

  STAGE(0, 0);
  asm volatile("s_waitcnt vmcnt(0)" ::: "memory");
  __builtin_amdgcn_s_barrier();
  for (int t = 0; t <= tmax; t++) {
    int cur = t & 1;
    if (t < tmax) STAGE(cur ^ 1, t + 1);
    {
      bool diag = (t == tmax);
      bool nf2 = !(diag && !(qc & 1));
      const short* Kc = &Ks[cur][0];
      const short* Vc = &Vs[cur][0];
      // ---- de-interleaved K fragment loads (pipeline the ds_reads) ----
      short8 kf0[8], kf1[8];
      #pragma unroll
      for (int kk = 0; kk < 8; kk++) {
        int gsl = ((2 * kk + hi) ^ swzk) * 8;
        kf0[kk] = *(const short8*)&Kc[l31 * 128 + gsl];
      }
      if (nf2) {
        #pragma unroll
        for (int kk = 0; kk < 8; kk++) {
          int gsl = ((2 * kk + hi) ^ swzk) * 8;
          kf1[kk] = *(const short8*)&Kc[l31 * 128 + 4096 + gsl];
        }
      }
      f32x16 s0 = (f32x16)0.0f, s1 = (f32x16)0.0f;
      __builtin_amdgcn_s_setprio(1);
      #pragma unroll
      for (int kk = 0; kk < 8; kk++)
        s0 = __builtin_amdgcn_mfma_f32_32x32x16_bf16(kf0[kk], qf[kk], s0, 0, 0, 0);
      if (nf2) {
        #pragma unroll
        for (int kk = 0; kk < 8; kk++)
          s1 = __builtin_amdgcn_mfma_f32_32x32x16_bf16(kf1[kk], qf[kk], s1, 0, 0, 0);
      }
      __builtin_amdgcn_s_setprio(0);
      if (diag) {
        int qrel = (qc & 1) * 32 + l31;
        #pragma unroll
        for (int r = 0; r < 16; r++) {
          int kvl = (r & 3) + 8 * (r >> 2) + 4 * hi;
          if (kvl > qrel) s0[r] = -INFINITY;
          if (kvl + 32 > qrel) s1[r] = -INFINITY;
        }
      }
      float t8[8];
      #pragma unroll
      for (int i = 0; i < 8; i++) t8[i] = fmaxf(s0[2 * i], s0[2 * i + 1]);
      if (nf2) {
        #pragma unroll
        for (int i = 0; i < 8; i++) t8[i] = fmaxf(t8[i], fmaxf(s1[2 * i], s1[2 * i + 1]));
      }
      float m01 = fmaxf(fmaxf(t8[0], t8[1]), fmaxf(t8[2], t8[3]));
      float m23 = fmaxf(fmaxf(t8[4], t8[5]), fmaxf(t8[6], t8[7]));
      float pmax = red_max32(fmaxf(m01, m23));
      if (!__all(pmax - m_run <= 11.0f)) {
        float mn = fmaxf(m_run, pmax);
        float al = __builtin_amdgcn_exp2f(m_run - mn);
        l_run *= al;
        #pragma unroll
        for (int m = 0; m < 4; m++) accT[m] *= al;
        m_run = mn;
      }
      #pragma unroll
      for (int r = 0; r < 16; r++) s0[r] = __builtin_amdgcn_exp2f(s0[r] - m_run);
      if (nf2) {
        #pragma unroll
        for (int r = 0; r < 16; r++) s1[r] = __builtin_amdgcn_exp2f(s1[r] - m_run);
      }
      float a8[8];
      #pragma unroll
      for (int i = 0; i < 8; i++) a8[i] = s0[2 * i] + s0[2 * i + 1];
      if (nf2) {
        #pragma unroll
        for (int i = 0; i < 8; i++) a8[i] += s1[2 * i] + s1[2 * i + 1];
      }
      float r01 = (a8[0] + a8[1]) + (a8[2] + a8[3]);
      float r23 = (a8[4] + a8[5]) + (a8[6] + a8[7]);
      l_run += red_add32(r01 + r23);

      auto packfrag = [&](const f32x16& sv, int rb) -> short8 {
        union { short8 hh; unsigned u[4]; } P;
        #pragma unroll
        for (int w = 0; w < 2; w++) {
          float a0 = sv[rb + 2 * w],     a1 = sv[rb + 2 * w + 1];
          float b0 = sv[rb + 4 + 2 * w], b1 = sv[rb + 4 + 2 * w + 1];
          unsigned X, Y;
          asm("v_cvt_pk_bf16_f32 %0, %1, %2" : "=v"(X) : "v"(a0), "v"(a1));
          asm("v_cvt_pk_bf16_f32 %0, %1, %2" : "=v"(Y) : "v"(b0), "v"(b1));
          swap32(X, Y);
          P.u[w]     = X;
          P.u[w + 2] = Y;
        }
        return P.hh;
      };
      // ---- de-interleaved PV: load 4 V frags, then 4 independent MFMAs ----
#define PVSTEP(g4, pg) do {                                                             \
        short8 vf[4];                                                                   \
        _Pragma("unroll")                                                               \
        for (int m = 0; m < 4; m++)                                                     \
          vf[m] = *(const short8*)&Vc[(m * 32 + l31) * 64 + (((2 * (g4) + hi) ^ swzv2) * 8)]; \
        _Pragma("unroll")                                                               \
        for (int m = 0; m < 4; m++)                                                     \
          accT[m] = __builtin_amdgcn_mfma_f32_32x32x16_bf16(vf[m], pg, accT[m], 0, 0, 0); \
      } while (0)
      short8 pg;
      __builtin_amdgcn_s_setprio(1);
      pg = packfrag(s0, 0); PVSTEP(0, pg);
      pg = packfrag(s0, 8); PVSTEP(1, pg);
      if (nf2) {
        pg = packfrag(s1, 0); PVSTEP(2, pg);
        pg = packfrag(s1, 8); PVSTEP(3, pg);
      }
      __builtin_amdgcn_s_setprio(0);
#undef PVSTEP
    }
    asm volatile("s_waitcnt vmcnt(0)" ::: "memory");
    __builtin_amdgcn_s_barrier();
  }
#undef STAGE

  // epilogue: O^T -> O via per-wave LDS transpose, coalesced bf16 store
  __syncthreads();
  float linv = 1.0f / l_run;
  float* T = (float*)(&Ks[0][0]) + wave * 1056;
  #pragma unroll
  for (int m = 0; m < 4; m++) {
    #pragma unroll
    for (int r = 0; r < 16; r++)
      T[((r & 3) + 8 * (r >> 2) + 4 * hi) * 33 + l31] = accT[m][r] * linv;
    asm volatile("" ::: "memory");
    #pragma unroll
    for (int it2 = 0; it2 < 4; it2++) {
      int q2 = it2 * 8 + (lane >> 3);
      int d8 = (lane & 7) * 4;
      short4v o;
      #pragma unroll
      for (int kq = 0; kq < 4; kq++) o[kq] = f2bf(T[(d8 + kq) * 33 + q2]);
      *(short4v*)&AO[((size_t)(b * 2048 + qbase + q2)) * 2048 + h * 128 + m * 32 + d8] = o;
    }
    asm volatile("" ::: "memory");
  }
}

// ---------------- launch ----------------
extern "C" void kernel_launch(void* const* d_in, const int* in_sizes, int n_in,
                              void* d_out, int out_size, void* d_ws, size_t ws_size,
                              hipStream_t stream) {
  (void)in_sizes; (void)n_in; (void)out_size; (void)ws_size;
  const float* x    = (const float*)d_in[0];
  const float* cosT = (const float*)d_in[1];
  const float* sinT = (const float*)d_in[2];
  // d_in[3] = mask (causal, structure known; unused)
  const float* wq = (const float*)d_in[4];
  const float* wk = (const float*)d_in[5];
  const float* wv = (const float*)d_in[6];
  const float* wo = (const float*)d_in[7];
  const float* qw = (const float*)d_in[8];
  const float* kw = (const float*)d_in[9];
  float* Out = (float*)d_out;

  char* w = (char*)d_ws;
  short* Xb    = (short*)(w + 0);           // 4096x2048 bf16          16777216 B
  short* WallT = (short*)(w + 16777216);    // [WqT;WkT;WvT] 3072x2048 12582912 B
  short* WoT   = (short*)(w + 29360128);    // 2048x2048                8388608 B
  short* QKV   = (short*)(w + 37748736);    // 4096x3072               25165824 B
  short* Qa    = (short*)(w + 62914560);    // (b,h,2048,128)          16777216 B
  short* Ka    = (short*)(w + 79691776);    // (b,g,2048,128)           4194304 B
  short* Vtr   = (short*)(w + 83886080);    // (b,g,128,2048)           4194304 B
  short* AO    = (short*)(w + 88080384);    // 4096x2048               16777216 B
  // total 104857600 B

  prep1<<<14336, 256, 0, stream>>>(x, wq, wk, wv, wo, Xb, WallT, WoT);
  gemm_bt<true><<<dim3(24, 32), 256, 0, stream>>>(Xb, WallT, QKV, 4096, 3072, 2048, 3072);
  prep2<<<22528, 256, 0, stream>>>(QKV, cosT, sinT, qw, kw, Qa, Ka, Vtr);
  attn14<<<512, 256, 0, stream>>>(Qa, Ka, Vtr, AO);
  gemm_bt<false><<<dim3(16, 32), 256, 0, stream>>>(AO, WoT, Out, 4096, 2048, 2048, 2048);
}